// Round 4
// baseline (177.942 us; speedup 1.0000x reference)
//
#include <hip/hip_runtime.h>

// Problem dims (ViT-Base LoRA-MoE qkv)
#define TOK 8192      // B*S = 32*256
#define DD  768       // in features
#define NOUT 2304     // 3*D
#define TT  8         // saved tasks
#define RR  16        // LoRA rank
#define KRANK 144     // T*R + R (per branch folded rank)

typedef __bf16 bf16;
typedef __bf16 bf16x4 __attribute__((ext_vector_type(4)));
typedef __bf16 bf16x8 __attribute__((ext_vector_type(8)));
typedef float  floatx4 __attribute__((ext_vector_type(4)));

__device__ __forceinline__ void gl_lds16(const void* g, void* l) {
    __builtin_amdgcn_global_load_lds((const __attribute__((address_space(1))) void*)g,
                                     (__attribute__((address_space(3))) void*)l, 16, 0, 0);
}

// ----------------------------------------------------------------- prep ----
// blocks 0..31: Frobenius norms of {A_q,B_q,A_v,B_v}[task]  (b>>3 selects
// tensor, b&7 selects task). blocks 32..3103: fp32->bf16 cast of x,
// 8 elems/thread (bf16x8 16B stores).  (unchanged, verified)
__global__ __launch_bounds__(256) void prep_kernel(
    const float* __restrict__ A_q, const float* __restrict__ B_q,
    const float* __restrict__ A_v, const float* __restrict__ B_v,
    const float* __restrict__ x, bf16* __restrict__ xb,
    float* __restrict__ norms)
{
    __shared__ float ws4[4];
    const int b = blockIdx.x;
    if (b < 32) {
        const float* base;
        switch (b >> 3) {
            case 0: base = A_q; break;
            case 1: base = B_q; break;
            case 2: base = A_v; break;
            default: base = B_v; break;
        }
        base += (b & 7) * (RR * DD);
        float s = 0.f;
        for (int i = threadIdx.x; i < RR * DD; i += 256) {
            float v = base[i];
            s = fmaf(v, v, s);
        }
        #pragma unroll
        for (int off = 32; off > 0; off >>= 1) s += __shfl_down(s, off);
        if ((threadIdx.x & 63) == 0) ws4[threadIdx.x >> 6] = s;
        __syncthreads();
        if (threadIdx.x == 0)
            norms[b] = sqrtf(ws4[0] + ws4[1] + ws4[2] + ws4[3]);
    } else {
        const int idx = ((b - 32) * 256 + threadIdx.x) * 8;
        const float4 v0 = *(const float4*)(x + idx);
        const float4 v1 = *(const float4*)(x + idx + 4);
        bf16x8 o = { (bf16)v0.x, (bf16)v0.y, (bf16)v0.z, (bf16)v0.w,
                     (bf16)v1.x, (bf16)v1.y, (bf16)v1.z, (bf16)v1.w };
        *(bf16x8*)(xb + idx) = o;
    }
}

// ----------------------------------------------------------------- fold ----
// Wc[row] = bf16(qkv_w[row] + sum_i c[row][i] * Acat[i][:]) for q/v thirds;
// plain bf16 cast for the k third. grid = (3, 288).  (unchanged, verified)
__global__ __launch_bounds__(256) void fold_kernel(
    const float* __restrict__ qkv_w,
    const float* __restrict__ A_q, const float* __restrict__ la_q,
    const float* __restrict__ B_q, const float* __restrict__ lb_q,
    const float* __restrict__ A_v, const float* __restrict__ la_v,
    const float* __restrict__ B_v, const float* __restrict__ lb_v,
    const float* __restrict__ gate_logits, const float* __restrict__ alpha,
    const float* __restrict__ norms, bf16* __restrict__ Wc)
{
    const int tid = threadIdx.x;
    const int d = blockIdx.x * 256 + tid;
    const int gy = blockIdx.y;

    if (gy >= 96 && gy < 192) {           // k third: pure cast
        const int rowbase = DD + (gy - 96) * 8;
        #pragma unroll
        for (int j = 0; j < 8; ++j) {
            const int row = rowbase + j;
            Wc[row * DD + d] = (bf16)qkv_w[row * DD + d];
        }
        return;
    }

    __shared__ float c_lds[8 * KRANK];
    __shared__ float sc_sh[TT];
    __shared__ float acur_sh;

    const bool is_v = (gy >= 192);
    const int e0 = (is_v ? gy - 192 : gy) * 8;
    const float* Astack = is_v ? A_v : A_q;
    const float* la     = is_v ? la_v : la_q;
    const float* Bmat   = is_v ? B_v : B_q;
    const float* lb     = is_v ? lb_v : lb_q;
    const float* nA     = norms + (is_v ? 16 : 0);
    const float* nB     = norms + (is_v ? 24 : 8);
    const int rowbase   = (is_v ? 2 * DD : 0) + e0;

    if (tid == 0) {
        float mx = gate_logits[0];
        for (int t = 1; t < TT; ++t) mx = fmaxf(mx, gate_logits[t]);
        float e[TT], s = 0.f;
        for (int t = 0; t < TT; ++t) { e[t] = __expf(gate_logits[t] - mx); s += e[t]; }
        for (int t = 0; t < TT; ++t) sc_sh[t] = (e[t] / s) / (nA[t] * nB[t]);
        acur_sh = alpha[TT];
    }
    __syncthreads();

    for (int idx = tid; idx < 8 * KRANK; idx += 256) {
        const int j = idx / KRANK, i = idx - j * KRANK;
        const int e = e0 + j;
        float v;
        if (i < TT * RR) {
            const int t = i >> 4, r = i & 15;
            v = sc_sh[t] * Bmat[(t * DD + e) * RR + r];
        } else {
            v = acur_sh * lb[e * RR + (i - TT * RR)];
        }
        c_lds[j * KRANK + i] = v;
    }
    __syncthreads();

    float acc[8] = {0.f, 0.f, 0.f, 0.f, 0.f, 0.f, 0.f, 0.f};

    for (int i = 0; i < TT * RR; i += 4) {
        const float a0 = Astack[(i + 0) * DD + d];
        const float a1 = Astack[(i + 1) * DD + d];
        const float a2 = Astack[(i + 2) * DD + d];
        const float a3 = Astack[(i + 3) * DD + d];
        #pragma unroll
        for (int j = 0; j < 8; ++j) {
            const float4 cv = *(const float4*)&c_lds[j * KRANK + i];
            acc[j] = fmaf(a0, cv.x, fmaf(a1, cv.y, fmaf(a2, cv.z, fmaf(a3, cv.w, acc[j]))));
        }
    }
    #pragma unroll
    for (int i = 0; i < RR; i += 4) {
        const float a0 = la[(i + 0) * DD + d];
        const float a1 = la[(i + 1) * DD + d];
        const float a2 = la[(i + 2) * DD + d];
        const float a3 = la[(i + 3) * DD + d];
        #pragma unroll
        for (int j = 0; j < 8; ++j) {
            const float4 cv = *(const float4*)&c_lds[j * KRANK + TT * RR + i];
            acc[j] = fmaf(a0, cv.x, fmaf(a1, cv.y, fmaf(a2, cv.z, fmaf(a3, cv.w, acc[j]))));
        }
    }

    #pragma unroll
    for (int j = 0; j < 8; ++j) {
        const int row = rowbase + j;
        Wc[row * DD + d] = (bf16)(qkv_w[row * DD + d] + acc[j]);
    }
}

// ----------------------------------------------------------------- gemm ----
// C[TOK,NOUT] = Xbf[TOK,DD] @ Wc[NOUT,DD]^T + bias.
// R10: triple-buffered 1-barrier-per-K-tile pipeline. Evidence: R6(2/CU,
// 2-barrier)=R9(3/CU, 2-barrier, fewer MFMA/barrier) ~= 44us at 31% MfmaUtil
// while MFMA floor=14us -> the cost scales with per-K-step sync count, not
// residency. Change: tile 128x288 BK=64 kept (all R6-proven chunk/swizzle/
// fragment layouts byte-identical), but 512 threads (8 waves, 32x144 each =
// R7-proven 2x9 mapping), LDS = 3 x 52KB = 156KB -> 1 block/CU, 2 waves/SIMD,
// grid 512 = exactly 2 residency rounds.
// Pipeline (prefetch distance 2, ONE barrier per tile, no boundary drain):
//   prologue: stage(0,t0); stage(1,t1)
//   iter t: vmcnt(6)   // drains stage(t) (older), leaves stage(t+1) in
//                      // flight; exact for 6-chunk waves, +1 conservative
//                      // for 7-chunk waves (their load was issued a full
//                      // tile earlier -> already complete)
//           s_barrier  // all waves' stage(t) drained + compute(t-1) done
//           stage((t+2)%3, t+2)   // WAR-safe: buf[(t+2)%3]=buf[(t-1)%3],
//                                 // whose readers all passed this barrier
//           compute tile t (26 ds_read_b128 + 72 MFMA per wave, setprio(1))
//   t=11: vmcnt(0) (stage(11) issued at t=9, long complete).
// RAW: stage(t) drained by own-wave counted vmcnt before barrier. 1 barrier
// per 72 MFMA/wave (vs R6's 2 per 72) and the drain point is ~2800cy after
// issue -> near-free.
__global__ __launch_bounds__(512, 2) void gemm_kernel(
    const bf16* __restrict__ A, const bf16* __restrict__ B,
    const float* __restrict__ bias, float* __restrict__ C)
{
    // 3 x (A 128x64 bf16 = 16KB + B 288x64 bf16 = 36KB) = 159744 B
    __shared__ __align__(16) char smem[159744];

    const int tid  = threadIdx.x;
    const int lane = tid & 63;
    const int wave = tid >> 6;          // 0..7

    // XCD swizzle: 512 blocks = 8 XCD x (8 m-tiles x 8 n-tiles)
    const int flat  = blockIdx.x;
    const int xcd   = flat & 7;
    const int local = flat >> 3;           // 0..63
    const int mb    = xcd * 8 + (local & 7);
    const int nb    = local >> 3;          // 0..7
    const int m0 = mb * 128;
    const int n0 = nb * 288;

    // 8 waves: 4M x 2N, each computes 32x144 (2x9 tiles of 16x16)
    const int wm = (wave >> 1) * 32;
    const int wn = (wave & 1) * 144;

    // staging: lane l -> slot l (16B) within a 1KB chunk (8 rows x 64 bf16).
    // logical row = l>>3, logical 16B chunk = (l&7) ^ (l>>3)  (XOR swizzle,
    // R6-verified 0 bank conflicts).
    const int srow = lane >> 3;                    // 0..7
    const int scol = ((lane & 7) ^ srow) * 8;      // swizzled col (bf16 units)

    floatx4 acc[2][9];
    #pragma unroll
    for (int i = 0; i < 2; ++i)
        #pragma unroll
        for (int j = 0; j < 9; ++j)
            acc[i][j] = (floatx4){0.f, 0.f, 0.f, 0.f};

    const bf16* const gA = A + (m0 + srow) * DD + scol;
    const bf16* const gB = B + (n0 + srow) * DD + scol;

    // 52 chunks/K-tile: 0..15 A (128 rows), 16..51 B (288 rows).
    // wave round-robin stride 8 -> counts 7/7/7/7/6/6/6/6.
    auto stage = [&](int buf, int kt) {
        bf16* la = (bf16*)(smem + buf * 53248);
        bf16* lb = (bf16*)(smem + buf * 53248 + 16384);
        const int k0 = kt * 64;
        for (int c = wave; c < 52; c += 8) {
            if (c < 16) gl_lds16(gA + c * 8 * DD + k0, la + c * 512);
            else        gl_lds16(gB + (c - 16) * 8 * DD + k0, lb + (c - 16) * 512);
        }
    };

    stage(0, 0);
    stage(1, 1);

    for (int kt = 0; kt < 12; ++kt) {
        if (kt < 11) {
            // drain stage(kt): all but the newest 6 (= stage(kt+1) for
            // 6-chunk waves; 7-chunk waves wait +1 long-issued load).
            asm volatile("s_waitcnt vmcnt(6)" ::: "memory");
        } else {
            asm volatile("s_waitcnt vmcnt(0)" ::: "memory");
        }
        __builtin_amdgcn_s_barrier();
        asm volatile("" ::: "memory");   // no LDS read hoists above barrier

        if (kt < 10) stage((kt + 2) % 3, kt + 2);   // post-barrier: WAR-safe

        const bf16* la = (bf16*)(smem + (kt % 3) * 53248);
        const bf16* lb = (bf16*)(smem + (kt % 3) * 53248 + 16384);

        __builtin_amdgcn_s_setprio(1);
        #pragma unroll
        for (int ks = 0; ks < 2; ++ks) {
            const int c_log = ks * 4 + (lane >> 4); // 16B chunk index 0..7
            bf16x8 af[2];
            #pragma unroll
            for (int mt = 0; mt < 2; ++mt) {
                const int r = wm + mt * 16 + (lane & 15);
                af[mt] = *(const bf16x8*)&la[r * 64 + ((c_log ^ (r & 7)) * 8)];
            }
            #pragma unroll
            for (int nt = 0; nt < 9; ++nt) {
                const int r = wn + nt * 16 + (lane & 15);
                const bf16x8 bfr = *(const bf16x8*)&lb[r * 64 + ((c_log ^ (r & 7)) * 8)];
                #pragma unroll
                for (int mt = 0; mt < 2; ++mt)
                    acc[mt][nt] = __builtin_amdgcn_mfma_f32_16x16x32_bf16(
                        af[mt], bfr, acc[mt][nt], 0, 0, 0);
            }
        }
        __builtin_amdgcn_s_setprio(0);
        asm volatile("" ::: "memory");   // LDS reads complete before release
    }

    // epilogue: direct stores. C/D layout col=lane&15, row=(lane>>4)*4+reg
    const int cr = (lane >> 4) * 4;
    const int cc = lane & 15;
    #pragma unroll
    for (int nt = 0; nt < 9; ++nt) {
        const int gn = n0 + wn + nt * 16 + cc;
        const float bv = bias[gn];
        #pragma unroll
        for (int mt = 0; mt < 2; ++mt) {
            const int gmb = m0 + wm + mt * 16 + cr;
            #pragma unroll
            for (int r = 0; r < 4; ++r)
                C[(gmb + r) * NOUT + gn] = acc[mt][nt][r] + bv;
        }
    }
}

// --------------------------------------------------------------- launch ----
extern "C" void kernel_launch(void* const* d_in, const int* in_sizes, int n_in,
                              void* d_out, int out_size, void* d_ws, size_t ws_size,
                              hipStream_t stream)
{
    const float* x           = (const float*)d_in[0];
    const float* qkv_w       = (const float*)d_in[1];
    const float* qkv_b       = (const float*)d_in[2];
    const float* la_q        = (const float*)d_in[3];
    const float* lb_q        = (const float*)d_in[4];
    const float* la_v        = (const float*)d_in[5];
    const float* lb_v        = (const float*)d_in[6];
    const float* A_q         = (const float*)d_in[7];
    const float* B_q         = (const float*)d_in[8];
    const float* A_v         = (const float*)d_in[9];
    const float* B_v         = (const float*)d_in[10];
    const float* gate_logits = (const float*)d_in[11];
    const float* alpha       = (const float*)d_in[12];
    float* out = (float*)d_out;

    char* ws = (char*)d_ws;
    bf16*  Xbf    = (bf16*)ws;                                  // 12,582,912 B
    bf16*  Wc     = (bf16*)(ws + 12582912);                     //  3,538,944 B
    float* norms  = (float*)(ws + 12582912 + 3538944);          // 32 floats

    prep_kernel<<<32 + TOK * DD / 2048, 256, 0, stream>>>(A_q, B_q, A_v, B_v,
                                                          x, Xbf, norms);
    fold_kernel<<<dim3(3, 288), 256, 0, stream>>>(qkv_w,
                                                  A_q, la_q, B_q, lb_q,
                                                  A_v, la_v, B_v, lb_v,
                                                  gate_logits, alpha, norms, Wc);
    gemm_kernel<<<512, 512, 0, stream>>>(Xbf, Wc, qkv_b, out);
}